// Round 1
// baseline (739.801 us; speedup 1.0000x reference)
//
#include <hip/hip_runtime.h>
#include <hip/hip_bf16.h>
#include <math.h>

// Problem constants
#define BATCH 8
#define IN_CH 512      // C, becomes sequence length L
#define L0 1024
#define FD 512         // d_model
#define L_SEQ 512
#define DI 1024
#define NS 16
#define RK 32
#define DCONV 4

// ---------------------------------------------------------------
// Kernel 1: depthwise conv (k=2, s=2) + transpose  -> h1t[b, f, c]
// ---------------------------------------------------------------
__global__ __launch_bounds__(256) void k_dw_transpose(
    const float* __restrict__ x, const float* __restrict__ dww,
    const float* __restrict__ dwb, float* __restrict__ h1t)
{
    int b = blockIdx.z;
    int c0 = blockIdx.y * 32;
    int f0 = blockIdx.x * 32;
    __shared__ float t[32][33];
    int tx = threadIdx.x;   // 0..31
    int ty = threadIdx.y;   // 0..7
#pragma unroll
    for (int i = 0; i < 4; ++i) {
        int cc = ty + 8 * i;
        int c = c0 + cc, f = f0 + tx;
        const float* xp = x + ((long)b * IN_CH + c) * L0 + 2 * f;
        t[cc][tx] = xp[0] * dww[c * 2 + 0] + xp[1] * dww[c * 2 + 1] + dwb[c];
    }
    __syncthreads();
#pragma unroll
    for (int i = 0; i < 4; ++i) {
        int ff = ty + 8 * i;
        h1t[((long)b * FD + f0 + ff) * IN_CH + c0 + tx] = t[tx][ff];
    }
}

// ---------------------------------------------------------------
// Generic fp32 GEMM (NT): C[m,n] = sum_k A[m,k] * B[n,k]
// Tiles 64x64, BK=16, 256 threads, each thread 4x4.
// Dims must be multiples of 64 (M,N) and 16 (K). (All uses satisfy this,
// except N=64 which is exactly one tile.)
// ---------------------------------------------------------------
#define BM 64
#define BN 64
#define BK 16

__global__ __launch_bounds__(256) void gemm_nt(
    const float* __restrict__ A, const float* __restrict__ B,
    float* __restrict__ C,
    int M, int N, int K, int lda, int ldb, int ldc,
    long sA, long sB, long sC)
{
    int bz = blockIdx.z;
    A += (long)bz * sA;
    B += (long)bz * sB;
    C += (long)bz * sC;
    int m0 = blockIdx.y * BM;
    int n0 = blockIdx.x * BN;

    __shared__ float As[BM][BK + 1];
    __shared__ float Bs[BN][BK + 1];

    int tid = threadIdx.x;
    int lr = tid >> 2;          // 0..63 row within tile
    int lk = (tid & 3) * 4;     // 0,4,8,12
    int tx = tid & 15;          // col group
    int ty = tid >> 4;          // row group

    float acc[4][4] = {};

    for (int k0 = 0; k0 < K; k0 += BK) {
        float4 av = *(const float4*)(A + (long)(m0 + lr) * lda + k0 + lk);
        As[lr][lk + 0] = av.x; As[lr][lk + 1] = av.y;
        As[lr][lk + 2] = av.z; As[lr][lk + 3] = av.w;
        float4 bv = *(const float4*)(B + (long)(n0 + lr) * ldb + k0 + lk);
        Bs[lr][lk + 0] = bv.x; Bs[lr][lk + 1] = bv.y;
        Bs[lr][lk + 2] = bv.z; Bs[lr][lk + 3] = bv.w;
        __syncthreads();
#pragma unroll
        for (int k = 0; k < BK; ++k) {
            float a[4], bb[4];
#pragma unroll
            for (int i = 0; i < 4; ++i) a[i] = As[ty + 16 * i][k];
#pragma unroll
            for (int j = 0; j < 4; ++j) bb[j] = Bs[tx + 16 * j][k];
#pragma unroll
            for (int i = 0; i < 4; ++i)
#pragma unroll
                for (int j = 0; j < 4; ++j)
                    acc[i][j] += a[i] * bb[j];
        }
        __syncthreads();
    }
#pragma unroll
    for (int i = 0; i < 4; ++i)
#pragma unroll
        for (int j = 0; j < 4; ++j)
            C[(long)(m0 + ty + 16 * i) * ldc + n0 + tx + 16 * j] = acc[i][j];
}

// ---------------------------------------------------------------
// Epilogue after pointwise GEMM (in-place on g2):
// h = 2*silu(bn(g2 + pw_b)) + pe(l, f)
// layout g2[b, l(=o), f], idx = ((b*512)+l)*512 + f
// ---------------------------------------------------------------
__global__ __launch_bounds__(256) void ep_h(
    float* __restrict__ g2, const float* __restrict__ pw_b,
    const float* __restrict__ bn_g, const float* __restrict__ bn_b,
    const float* __restrict__ bn_m, const float* __restrict__ bn_v)
{
    int idx = blockIdx.x * 256 + threadIdx.x;
    int f = idx & 511;
    int l = (idx >> 9) & 511;
    float v = g2[idx] + pw_b[l];
    float sc = bn_g[l] * rsqrtf(bn_v[l] + 1e-5f);
    v = (v - bn_m[l]) * sc + bn_b[l];
    v = v / (1.f + __expf(-v));               // silu
    int i2 = f & ~1;
    float dv = __expf((float)i2 * (-9.210340371976184f / 512.f));
    float ang = (float)l * dv;
    float pe = (f & 1) ? cosf(ang) : sinf(ang);
    g2[idx] = 2.f * v + pe;
}

// ---------------------------------------------------------------
// Causal depthwise conv k=4 over sequence + SiLU.
// xz[b,l,0:1024] is x_in; output xc[b,l,d].
// ---------------------------------------------------------------
__global__ __launch_bounds__(256) void ep_conv_silu(
    const float* __restrict__ xz, const float* __restrict__ cw,
    const float* __restrict__ cb, float* __restrict__ xc)
{
    int idx = blockIdx.x * 256 + threadIdx.x;   // B*L*DI
    int d = idx & (DI - 1);
    int l = (idx >> 10) & (L_SEQ - 1);
    int b = idx >> 19;
    const float* xin = xz + ((long)b * L_SEQ) * (2 * DI) + d;
    float acc = cb[d];
#pragma unroll
    for (int k = 0; k < 4; ++k) {
        int ls = l - 3 + k;
        if (ls >= 0) acc += cw[d * 4 + k] * xin[(long)ls * (2 * DI)];
    }
    xc[idx] = acc / (1.f + __expf(-acc));
}

// ---------------------------------------------------------------
// softplus(dt + bias) in-place on dtb
// ---------------------------------------------------------------
__global__ __launch_bounds__(256) void ep_softplus(
    float* __restrict__ dtb, const float* __restrict__ dt_b)
{
    int idx = blockIdx.x * 256 + threadIdx.x;   // B*L*DI
    int d = idx & (DI - 1);
    float v = dtb[idx] + dt_b[d];
    dtb[idx] = fmaxf(v, 0.f) + log1pf(expf(-fabsf(v)));
}

// ---------------------------------------------------------------
// SSM scan, fused with D-residual and z-gating.
// grid (DI/256, B), block 256. One thread per (b, d).
// ---------------------------------------------------------------
__global__ __launch_bounds__(256) void k_scan(
    const float* __restrict__ dtb, const float* __restrict__ xc,
    const float* __restrict__ xdbl, const float* __restrict__ xz,
    const float* __restrict__ A_log, const float* __restrict__ Dv,
    float* __restrict__ ybuf)
{
    int b = blockIdx.y;
    int d = blockIdx.x * 256 + threadIdx.x;
    float Arow[NS];
#pragma unroll
    for (int n = 0; n < NS; ++n) Arow[n] = -__expf(A_log[d * NS + n]);
    float Dd = Dv[d];
    float h[NS];
#pragma unroll
    for (int n = 0; n < NS; ++n) h[n] = 0.f;

    __shared__ float sbc[8][32];
    for (int l0 = 0; l0 < L_SEQ; l0 += 8) {
        __syncthreads();
        int r = threadIdx.x >> 5, c = threadIdx.x & 31;
        sbc[r][c] = xdbl[((long)(b * L_SEQ + l0 + r)) * 64 + 32 + c];
        __syncthreads();
#pragma unroll 1
        for (int ll = 0; ll < 8; ++ll) {
            int l = l0 + ll;
            long row = (long)b * L_SEQ + l;
            float dtv = dtb[row * DI + d];
            float xcv = xc[row * DI + d];
            float y = 0.f;
#pragma unroll
            for (int n = 0; n < NS; ++n) {
                float dA = __expf(dtv * Arow[n]);
                h[n] = dA * h[n] + dtv * sbc[ll][n] * xcv;
                y += h[n] * sbc[ll][16 + n];
            }
            float zv = xz[row * (2 * DI) + DI + d];
            float g = zv / (1.f + __expf(-zv));
            ybuf[row * DI + d] = (y + xcv * Dd) * g;
        }
    }
}

// ---------------------------------------------------------------
extern "C" void kernel_launch(void* const* d_in, const int* in_sizes, int n_in,
                              void* d_out, int out_size, void* d_ws, size_t ws_size,
                              hipStream_t stream)
{
    const float* x        = (const float*)d_in[0];
    const float* dw_w     = (const float*)d_in[1];
    const float* dw_b     = (const float*)d_in[2];
    const float* pw_w     = (const float*)d_in[3];
    const float* pw_b     = (const float*)d_in[4];
    const float* bn_g     = (const float*)d_in[5];
    const float* bn_b     = (const float*)d_in[6];
    const float* bn_m     = (const float*)d_in[7];
    const float* bn_v     = (const float*)d_in[8];
    const float* in_proj_w  = (const float*)d_in[9];
    const float* conv1d_w   = (const float*)d_in[10];
    const float* conv1d_b   = (const float*)d_in[11];
    const float* x_proj_w   = (const float*)d_in[12];
    const float* dt_proj_w  = (const float*)d_in[13];
    const float* dt_proj_b  = (const float*)d_in[14];
    const float* A_log      = (const float*)d_in[15];
    const float* Dvec       = (const float*)d_in[16];
    const float* out_proj_w = (const float*)d_in[17];
    float* out = (float*)d_out;

    char* ws = (char*)d_ws;
    // layout (bytes); dtb reuses the h1t+g2 region (dead by then)
    float* h1t  = (float*)(ws + 0);              //  8 MB  [B][FD][C]
    float* g2   = (float*)(ws + 8388608);        //  8 MB  [B][L][FD]  (becomes h)
    float* dtb  = (float*)(ws + 0);              // 16 MB  [B][L][DI]  (reuse)
    float* xz   = (float*)(ws + 16777216);       // 32 MB  [B][L][2*DI]
    float* xc   = (float*)(ws + 50331648);       // 16 MB  [B][L][DI]
    float* xdbl = (float*)(ws + 67108864);       //  1 MB  [B][L][64]
    float* ybuf = (float*)(ws + 68157440);       // 16 MB  [B][L][DI]

    // 1. depthwise + transpose
    {
        dim3 g(FD / 32, IN_CH / 32, BATCH), blk(32, 8);
        hipLaunchKernelGGL(k_dw_transpose, g, blk, 0, stream, x, dw_w, dw_b, h1t);
    }
    // 2. pointwise GEMM (batched): g2[b,o,f] = sum_c pw[o,c] * h1t[b,f,c]
    {
        dim3 g(FD / BN, IN_CH / BM, BATCH);
        hipLaunchKernelGGL(gemm_nt, g, dim3(256), 0, stream,
                           pw_w, h1t, g2, IN_CH, FD, IN_CH, IN_CH, IN_CH, FD,
                           0L, (long)FD * IN_CH, (long)IN_CH * FD);
    }
    // 3. epilogue: bias+BN+SiLU, 2x + PE  (in-place on g2 -> h)
    hipLaunchKernelGGL(ep_h, dim3(BATCH * L_SEQ * FD / 256), dim3(256), 0, stream,
                       g2, pw_b, bn_g, bn_b, bn_m, bn_v);
    // 4. in_proj GEMM: xz[m, j] = sum_f h[m,f] * in_proj_w[j,f]; M=4096,N=2048,K=512
    {
        dim3 g(2048 / BN, (BATCH * L_SEQ) / BM, 1);
        hipLaunchKernelGGL(gemm_nt, g, dim3(256), 0, stream,
                           g2, in_proj_w, xz, BATCH * L_SEQ, 2048, FD, FD, FD, 2048,
                           0L, 0L, 0L);
    }
    // 5. causal conv + silu -> xc
    hipLaunchKernelGGL(ep_conv_silu, dim3(BATCH * L_SEQ * DI / 256), dim3(256), 0, stream,
                       xz, conv1d_w, conv1d_b, xc);
    // 6. x_proj GEMM: xdbl[m, 0:64] ; M=4096, N=64, K=1024
    {
        dim3 g(64 / BN, (BATCH * L_SEQ) / BM, 1);
        hipLaunchKernelGGL(gemm_nt, g, dim3(256), 0, stream,
                           xc, x_proj_w, xdbl, BATCH * L_SEQ, 64, DI, DI, DI, 64,
                           0L, 0L, 0L);
    }
    // 7. dt_proj GEMM: dtb[m, d] = sum_r xdbl[m,r]*dt_proj_w[d,r]; K=32
    {
        dim3 g(DI / BN, (BATCH * L_SEQ) / BM, 1);
        hipLaunchKernelGGL(gemm_nt, g, dim3(256), 0, stream,
                           xdbl, dt_proj_w, dtb, BATCH * L_SEQ, DI, RK, 64, RK, DI,
                           0L, 0L, 0L);
    }
    // 8. softplus (in-place)
    hipLaunchKernelGGL(ep_softplus, dim3(BATCH * L_SEQ * DI / 256), dim3(256), 0, stream,
                       dtb, dt_proj_b);
    // 9. scan (fused D-residual + z-gate)
    {
        dim3 g(DI / 256, BATCH);
        hipLaunchKernelGGL(k_scan, g, dim3(256), 0, stream,
                           dtb, xc, xdbl, xz, A_log, Dvec, ybuf);
    }
    // 10. out_proj GEMM: out[m, f] = sum_d ybuf[m,d]*out_proj_w[f,d]
    {
        dim3 g(FD / BN, (BATCH * L_SEQ) / BM, 1);
        hipLaunchKernelGGL(gemm_nt, g, dim3(256), 0, stream,
                           ybuf, out_proj_w, out, BATCH * L_SEQ, FD, DI, DI, DI, FD,
                           0L, 0L, 0L);
    }
}

// Round 2
// 618.457 us; speedup vs baseline: 1.1962x; 1.1962x over previous
//
#include <hip/hip_runtime.h>
#include <hip/hip_bf16.h>
#include <math.h>

// Problem constants
#define BATCH 8
#define IN_CH 512      // C, becomes sequence length L
#define L0 1024
#define FD 512         // d_model
#define L_SEQ 512
#define DI 1024
#define NS 16
#define RK 32
#define DCONV 4

// ---------------------------------------------------------------
// Kernel 1: depthwise conv (k=2, s=2) + transpose  -> h1t[b, f, c]
// ---------------------------------------------------------------
__global__ __launch_bounds__(256) void k_dw_transpose(
    const float* __restrict__ x, const float* __restrict__ dww,
    const float* __restrict__ dwb, float* __restrict__ h1t)
{
    int b = blockIdx.z;
    int c0 = blockIdx.y * 32;
    int f0 = blockIdx.x * 32;
    __shared__ float t[32][33];
    int tx = threadIdx.x;   // 0..31
    int ty = threadIdx.y;   // 0..7
#pragma unroll
    for (int i = 0; i < 4; ++i) {
        int cc = ty + 8 * i;
        int c = c0 + cc, f = f0 + tx;
        const float* xp = x + ((long)b * IN_CH + c) * L0 + 2 * f;
        t[cc][tx] = xp[0] * dww[c * 2 + 0] + xp[1] * dww[c * 2 + 1] + dwb[c];
    }
    __syncthreads();
#pragma unroll
    for (int i = 0; i < 4; ++i) {
        int ff = ty + 8 * i;
        h1t[((long)b * FD + f0 + ff) * IN_CH + c0 + tx] = t[tx][ff];
    }
}

// ---------------------------------------------------------------
// Generic fp32 GEMM (NT): C[m,n] = sum_k A[m,k] * B[n,k]
// Tiles 64x64, BK=16, 256 threads, each thread 4x4.
// ---------------------------------------------------------------
#define BM 64
#define BN 64
#define BK 16

__global__ __launch_bounds__(256) void gemm_nt(
    const float* __restrict__ A, const float* __restrict__ B,
    float* __restrict__ C,
    int M, int N, int K, int lda, int ldb, int ldc,
    long sA, long sB, long sC)
{
    int bz = blockIdx.z;
    A += (long)bz * sA;
    B += (long)bz * sB;
    C += (long)bz * sC;
    int m0 = blockIdx.y * BM;
    int n0 = blockIdx.x * BN;

    __shared__ float As[BM][BK + 1];
    __shared__ float Bs[BN][BK + 1];

    int tid = threadIdx.x;
    int lr = tid >> 2;          // 0..63 row within tile
    int lk = (tid & 3) * 4;     // 0,4,8,12
    int tx = tid & 15;          // col group
    int ty = tid >> 4;          // row group

    float acc[4][4] = {};

    for (int k0 = 0; k0 < K; k0 += BK) {
        float4 av = *(const float4*)(A + (long)(m0 + lr) * lda + k0 + lk);
        As[lr][lk + 0] = av.x; As[lr][lk + 1] = av.y;
        As[lr][lk + 2] = av.z; As[lr][lk + 3] = av.w;
        float4 bv = *(const float4*)(B + (long)(n0 + lr) * ldb + k0 + lk);
        Bs[lr][lk + 0] = bv.x; Bs[lr][lk + 1] = bv.y;
        Bs[lr][lk + 2] = bv.z; Bs[lr][lk + 3] = bv.w;
        __syncthreads();
#pragma unroll
        for (int k = 0; k < BK; ++k) {
            float a[4], bb[4];
#pragma unroll
            for (int i = 0; i < 4; ++i) a[i] = As[ty + 16 * i][k];
#pragma unroll
            for (int j = 0; j < 4; ++j) bb[j] = Bs[tx + 16 * j][k];
#pragma unroll
            for (int i = 0; i < 4; ++i)
#pragma unroll
                for (int j = 0; j < 4; ++j)
                    acc[i][j] += a[i] * bb[j];
        }
        __syncthreads();
    }
#pragma unroll
    for (int i = 0; i < 4; ++i)
#pragma unroll
        for (int j = 0; j < 4; ++j)
            C[(long)(m0 + ty + 16 * i) * ldc + n0 + tx + 16 * j] = acc[i][j];
}

// ---------------------------------------------------------------
// Epilogue after pointwise GEMM (in-place on g2):
// h = 2*silu(bn(g2 + pw_b)) + pe(l, f)
// ---------------------------------------------------------------
__global__ __launch_bounds__(256) void ep_h(
    float* __restrict__ g2, const float* __restrict__ pw_b,
    const float* __restrict__ bn_g, const float* __restrict__ bn_b,
    const float* __restrict__ bn_m, const float* __restrict__ bn_v)
{
    int idx = blockIdx.x * 256 + threadIdx.x;
    int f = idx & 511;
    int l = (idx >> 9) & 511;
    float v = g2[idx] + pw_b[l];
    float sc = bn_g[l] * rsqrtf(bn_v[l] + 1e-5f);
    v = (v - bn_m[l]) * sc + bn_b[l];
    v = v / (1.f + __expf(-v));               // silu
    int i2 = f & ~1;
    float dv = __expf((float)i2 * (-9.210340371976184f / 512.f));
    float ang = (float)l * dv;
    float pe = (f & 1) ? cosf(ang) : sinf(ang);
    g2[idx] = 2.f * v + pe;
}

// ---------------------------------------------------------------
// Causal depthwise conv k=4 over sequence + SiLU.
// ---------------------------------------------------------------
__global__ __launch_bounds__(256) void ep_conv_silu(
    const float* __restrict__ xz, const float* __restrict__ cw,
    const float* __restrict__ cb, float* __restrict__ xc)
{
    int idx = blockIdx.x * 256 + threadIdx.x;   // B*L*DI
    int d = idx & (DI - 1);
    int l = (idx >> 10) & (L_SEQ - 1);
    int b = idx >> 19;
    const float* xin = xz + ((long)b * L_SEQ) * (2 * DI) + d;
    float acc = cb[d];
#pragma unroll
    for (int k = 0; k < 4; ++k) {
        int ls = l - 3 + k;
        if (ls >= 0) acc += cw[d * 4 + k] * xin[(long)ls * (2 * DI)];
    }
    xc[idx] = acc / (1.f + __expf(-acc));
}

// ---------------------------------------------------------------
// softplus(dt + bias) in-place on dtb
// ---------------------------------------------------------------
__global__ __launch_bounds__(256) void ep_softplus(
    float* __restrict__ dtb, const float* __restrict__ dt_b)
{
    int idx = blockIdx.x * 256 + threadIdx.x;   // B*L*DI
    int d = idx & (DI - 1);
    float v = dtb[idx] + dt_b[d];
    dtb[idx] = fmaxf(v, 0.f) + log1pf(expf(-fabsf(v)));
}

// ---------------------------------------------------------------
// SSM scan v2: state-parallel. One thread per (b, d, n).
// block 256 = 16 d-channels x 16 states; grid (DI/16, B) = 512 blocks
// => 2048 waves = 8 waves/CU. Explicit next-step prefetch so the
// loop-carried chain is just exp->fma.
// ---------------------------------------------------------------
__global__ __launch_bounds__(256) void k_scan(
    const float* __restrict__ dtb, const float* __restrict__ xc,
    const float* __restrict__ xdbl, const float* __restrict__ xz,
    const float* __restrict__ A_log, const float* __restrict__ Dv,
    float* __restrict__ ybuf)
{
    int b = blockIdx.y;
    int tid = threadIdx.x;
    int n = tid & 15;
    int dg = tid >> 4;              // 0..15
    int d = blockIdx.x * 16 + dg;

    float An = -__expf(A_log[d * NS + n]);
    float Dd = Dv[d];
    float h = 0.f;

    long rbase = (long)b * L_SEQ;
    // prefetch l=0
    long row = rbase * DI + d;
    long brow = rbase * 64;
    float dt_c = dtb[row];
    float xc_c = xc[row];
    float B_c  = xdbl[brow + RK + n];
    float C_c  = xdbl[brow + RK + NS + n];
    float z_c  = xz[rbase * (2 * DI) + DI + d];

    for (int l = 0; l < L_SEQ; ++l) {
        int ln = (l + 1 < L_SEQ) ? (l + 1) : (L_SEQ - 1);
        long rown = (rbase + ln) * DI + d;
        long brown = (rbase + ln) * 64;
        // issue next-step loads (independent of h-chain)
        float dt_n = dtb[rown];
        float xc_n = xc[rown];
        float B_n  = xdbl[brown + RK + n];
        float C_n  = xdbl[brown + RK + NS + n];
        float z_n  = xz[(rbase + ln) * (2 * DI) + DI + d];

        float dA = __expf(dt_c * An);
        h = fmaf(dA, h, dt_c * B_c * xc_c);
        float p = h * C_c;
        p += __shfl_xor(p, 1);
        p += __shfl_xor(p, 2);
        p += __shfl_xor(p, 4);
        p += __shfl_xor(p, 8);
        if (n == 0) {
            float g = z_c / (1.f + __expf(-z_c));
            ybuf[(rbase + l) * DI + d] = (p + xc_c * Dd) * g;
        }
        dt_c = dt_n; xc_c = xc_n; B_c = B_n; C_c = C_n; z_c = z_n;
    }
}

// ---------------------------------------------------------------
extern "C" void kernel_launch(void* const* d_in, const int* in_sizes, int n_in,
                              void* d_out, int out_size, void* d_ws, size_t ws_size,
                              hipStream_t stream)
{
    const float* x        = (const float*)d_in[0];
    const float* dw_w     = (const float*)d_in[1];
    const float* dw_b     = (const float*)d_in[2];
    const float* pw_w     = (const float*)d_in[3];
    const float* pw_b     = (const float*)d_in[4];
    const float* bn_g     = (const float*)d_in[5];
    const float* bn_b     = (const float*)d_in[6];
    const float* bn_m     = (const float*)d_in[7];
    const float* bn_v     = (const float*)d_in[8];
    const float* in_proj_w  = (const float*)d_in[9];
    const float* conv1d_w   = (const float*)d_in[10];
    const float* conv1d_b   = (const float*)d_in[11];
    const float* x_proj_w   = (const float*)d_in[12];
    const float* dt_proj_w  = (const float*)d_in[13];
    const float* dt_proj_b  = (const float*)d_in[14];
    const float* A_log      = (const float*)d_in[15];
    const float* Dvec       = (const float*)d_in[16];
    const float* out_proj_w = (const float*)d_in[17];
    float* out = (float*)d_out;

    char* ws = (char*)d_ws;
    float* h1t  = (float*)(ws + 0);              //  8 MB  [B][FD][C]
    float* g2   = (float*)(ws + 8388608);        //  8 MB  [B][L][FD]  (becomes h)
    float* dtb  = (float*)(ws + 0);              // 16 MB  [B][L][DI]  (reuse)
    float* xz   = (float*)(ws + 16777216);       // 32 MB  [B][L][2*DI]
    float* xc   = (float*)(ws + 50331648);       // 16 MB  [B][L][DI]
    float* xdbl = (float*)(ws + 67108864);       //  1 MB  [B][L][64]
    float* ybuf = (float*)(ws + 68157440);       // 16 MB  [B][L][DI]

    // 1. depthwise + transpose
    {
        dim3 g(FD / 32, IN_CH / 32, BATCH), blk(32, 8);
        hipLaunchKernelGGL(k_dw_transpose, g, blk, 0, stream, x, dw_w, dw_b, h1t);
    }
    // 2. pointwise GEMM (batched)
    {
        dim3 g(FD / BN, IN_CH / BM, BATCH);
        hipLaunchKernelGGL(gemm_nt, g, dim3(256), 0, stream,
                           pw_w, h1t, g2, IN_CH, FD, IN_CH, IN_CH, IN_CH, FD,
                           0L, (long)FD * IN_CH, (long)IN_CH * FD);
    }
    // 3. epilogue: bias+BN+SiLU, 2x + PE
    hipLaunchKernelGGL(ep_h, dim3(BATCH * L_SEQ * FD / 256), dim3(256), 0, stream,
                       g2, pw_b, bn_g, bn_b, bn_m, bn_v);
    // 4. in_proj GEMM
    {
        dim3 g(2048 / BN, (BATCH * L_SEQ) / BM, 1);
        hipLaunchKernelGGL(gemm_nt, g, dim3(256), 0, stream,
                           g2, in_proj_w, xz, BATCH * L_SEQ, 2048, FD, FD, FD, 2048,
                           0L, 0L, 0L);
    }
    // 5. causal conv + silu -> xc
    hipLaunchKernelGGL(ep_conv_silu, dim3(BATCH * L_SEQ * DI / 256), dim3(256), 0, stream,
                       xz, conv1d_w, conv1d_b, xc);
    // 6. x_proj GEMM
    {
        dim3 g(64 / BN, (BATCH * L_SEQ) / BM, 1);
        hipLaunchKernelGGL(gemm_nt, g, dim3(256), 0, stream,
                           xc, x_proj_w, xdbl, BATCH * L_SEQ, 64, DI, DI, DI, 64,
                           0L, 0L, 0L);
    }
    // 7. dt_proj GEMM
    {
        dim3 g(DI / BN, (BATCH * L_SEQ) / BM, 1);
        hipLaunchKernelGGL(gemm_nt, g, dim3(256), 0, stream,
                           xdbl, dt_proj_w, dtb, BATCH * L_SEQ, DI, RK, 64, RK, DI,
                           0L, 0L, 0L);
    }
    // 8. softplus (in-place)
    hipLaunchKernelGGL(ep_softplus, dim3(BATCH * L_SEQ * DI / 256), dim3(256), 0, stream,
                       dtb, dt_proj_b);
    // 9. scan v2 (state-parallel, fused D-residual + z-gate)
    {
        dim3 g(DI / 16, BATCH);
        hipLaunchKernelGGL(k_scan, g, dim3(256), 0, stream,
                           dtb, xc, xdbl, xz, A_log, Dvec, ybuf);
    }
    // 10. out_proj GEMM
    {
        dim3 g(FD / BN, (BATCH * L_SEQ) / BM, 1);
        hipLaunchKernelGGL(gemm_nt, g, dim3(256), 0, stream,
                           ybuf, out_proj_w, out, BATCH * L_SEQ, FD, DI, DI, DI, FD,
                           0L, 0L, 0L);
    }
}

// Round 3
// 393.315 us; speedup vs baseline: 1.8809x; 1.5724x over previous
//
#include <hip/hip_runtime.h>
#include <hip/hip_bf16.h>
#include <math.h>

#define BATCH 8
#define IN_CH 512
#define L0 1024
#define FD 512
#define L_SEQ 512
#define DI 1024
#define NS 16
#define RK 32

typedef __attribute__((ext_vector_type(4))) float f32x4;
typedef __attribute__((ext_vector_type(8))) short s16x8;

__device__ __forceinline__ unsigned short f2bf(float f) {
    union { float f; unsigned int u; } v; v.f = f;
    unsigned int u = v.u;
    return (unsigned short)((u + 0x7FFFu + ((u >> 16) & 1u)) >> 16);  // RNE
}
__device__ __forceinline__ unsigned int pk2(float x, float y) {
    return (unsigned int)f2bf(x) | ((unsigned int)f2bf(y) << 16);
}

// ---------------------------------------------------------------
// Kernel 1: depthwise conv (k=2, s=2) + transpose  -> h1t[b, f, c]
// ---------------------------------------------------------------
__global__ __launch_bounds__(256) void k_dw_transpose(
    const float* __restrict__ x, const float* __restrict__ dww,
    const float* __restrict__ dwb, float* __restrict__ h1t)
{
    int b = blockIdx.z;
    int c0 = blockIdx.y * 32;
    int f0 = blockIdx.x * 32;
    __shared__ float t[32][33];
    int tx = threadIdx.x, ty = threadIdx.y;
#pragma unroll
    for (int i = 0; i < 4; ++i) {
        int cc = ty + 8 * i;
        int c = c0 + cc, f = f0 + tx;
        const float* xp = x + ((long)b * IN_CH + c) * L0 + 2 * f;
        t[cc][tx] = xp[0] * dww[c * 2 + 0] + xp[1] * dww[c * 2 + 1] + dwb[c];
    }
    __syncthreads();
#pragma unroll
    for (int i = 0; i < 4; ++i) {
        int ff = ty + 8 * i;
        h1t[((long)b * FD + f0 + ff) * IN_CH + c0 + tx] = t[tx][ff];
    }
}

// ---------------------------------------------------------------
// bf16 MFMA GEMM (NT): C[m,n] = sum_k A[m,k]*B[n,k], fp32 in/out.
// 128x128 tile, BK=32, 256 threads = 4 waves (2x2 of 64x64).
// fp32 -> bf16 conversion during LDS staging.
// M,N multiples of 128; K multiple of 32.
// ---------------------------------------------------------------
__global__ __launch_bounds__(256) void gemm_bf16(
    const float* __restrict__ A, const float* __restrict__ B,
    float* __restrict__ C,
    int K, int lda, int ldb, int ldc, long sA, long sB, long sC)
{
    int bz = blockIdx.z;
    A += (long)bz * sA; B += (long)bz * sB; C += (long)bz * sC;
    int m0 = blockIdx.y * 128, n0 = blockIdx.x * 128;

    __shared__ __align__(16) unsigned short As[128][40];  // pad: stride 80B -> bank stride 20
    __shared__ __align__(16) unsigned short Bs[128][40];

    int tid = threadIdx.x;
    int row = tid >> 1, half = tid & 1;       // staging: 2 threads/row, 16 floats each
    int lane = tid & 63, wid = tid >> 6;
    int wm = wid >> 1, wn = wid & 1;          // 2x2 waves of 64x64
    int lm = lane & 15, g = lane >> 4;

    f32x4 zero = {0.f, 0.f, 0.f, 0.f};
    f32x4 acc[4][4];
#pragma unroll
    for (int i = 0; i < 4; ++i)
#pragma unroll
        for (int j = 0; j < 4; ++j) acc[i][j] = zero;

    const float* ga = A + (long)(m0 + row) * lda + half * 16;
    const float* gb = B + (long)(n0 + row) * ldb + half * 16;

    for (int k0 = 0; k0 < K; k0 += 32) {
        float4 a0 = *(const float4*)(ga + k0);
        float4 a1 = *(const float4*)(ga + k0 + 4);
        float4 a2 = *(const float4*)(ga + k0 + 8);
        float4 a3 = *(const float4*)(ga + k0 + 12);
        float4 b0 = *(const float4*)(gb + k0);
        float4 b1 = *(const float4*)(gb + k0 + 4);
        float4 b2 = *(const float4*)(gb + k0 + 8);
        float4 b3 = *(const float4*)(gb + k0 + 12);
        uint4 pa0, pa1, pb0, pb1;
        pa0.x = pk2(a0.x, a0.y); pa0.y = pk2(a0.z, a0.w);
        pa0.z = pk2(a1.x, a1.y); pa0.w = pk2(a1.z, a1.w);
        pa1.x = pk2(a2.x, a2.y); pa1.y = pk2(a2.z, a2.w);
        pa1.z = pk2(a3.x, a3.y); pa1.w = pk2(a3.z, a3.w);
        pb0.x = pk2(b0.x, b0.y); pb0.y = pk2(b0.z, b0.w);
        pb0.z = pk2(b1.x, b1.y); pb0.w = pk2(b1.z, b1.w);
        pb1.x = pk2(b2.x, b2.y); pb1.y = pk2(b2.z, b2.w);
        pb1.z = pk2(b3.x, b3.y); pb1.w = pk2(b3.z, b3.w);
        *(uint4*)&As[row][half * 16]     = pa0;
        *(uint4*)&As[row][half * 16 + 8] = pa1;
        *(uint4*)&Bs[row][half * 16]     = pb0;
        *(uint4*)&Bs[row][half * 16 + 8] = pb1;
        __syncthreads();

        s16x8 av[4], bv[4];
#pragma unroll
        for (int im = 0; im < 4; ++im)
            av[im] = *(const s16x8*)&As[wm * 64 + im * 16 + lm][g * 8];
#pragma unroll
        for (int jn = 0; jn < 4; ++jn)
            bv[jn] = *(const s16x8*)&Bs[wn * 64 + jn * 16 + lm][g * 8];
#pragma unroll
        for (int im = 0; im < 4; ++im)
#pragma unroll
            for (int jn = 0; jn < 4; ++jn)
                acc[im][jn] = __builtin_amdgcn_mfma_f32_16x16x32_bf16(
                    av[im], bv[jn], acc[im][jn], 0, 0, 0);
        __syncthreads();
    }
    // C/D layout (verified m89): col = lane&15, row = (lane>>4)*4 + reg
#pragma unroll
    for (int im = 0; im < 4; ++im)
#pragma unroll
        for (int jn = 0; jn < 4; ++jn)
#pragma unroll
            for (int r = 0; r < 4; ++r)
                C[(long)(m0 + wm * 64 + im * 16 + g * 4 + r) * ldc
                  + n0 + wn * 64 + jn * 16 + lm] = acc[im][jn][r];
}

// ---------------------------------------------------------------
// Generic fp32 GEMM (NT) for the two small GEMMs (x_proj, dt_proj).
// ---------------------------------------------------------------
#define BM 64
#define BN 64
#define BK 16

__global__ __launch_bounds__(256) void gemm_nt(
    const float* __restrict__ A, const float* __restrict__ B,
    float* __restrict__ C,
    int M, int N, int K, int lda, int ldb, int ldc,
    long sA, long sB, long sC)
{
    int bz = blockIdx.z;
    A += (long)bz * sA; B += (long)bz * sB; C += (long)bz * sC;
    int m0 = blockIdx.y * BM;
    int n0 = blockIdx.x * BN;

    __shared__ float Asf[BM][BK + 1];
    __shared__ float Bsf[BN][BK + 1];

    int tid = threadIdx.x;
    int lr = tid >> 2;
    int lk = (tid & 3) * 4;
    int tx = tid & 15;
    int ty = tid >> 4;

    float acc[4][4] = {};

    for (int k0 = 0; k0 < K; k0 += BK) {
        float4 av = *(const float4*)(A + (long)(m0 + lr) * lda + k0 + lk);
        Asf[lr][lk + 0] = av.x; Asf[lr][lk + 1] = av.y;
        Asf[lr][lk + 2] = av.z; Asf[lr][lk + 3] = av.w;
        float4 bv = *(const float4*)(B + (long)(n0 + lr) * ldb + k0 + lk);
        Bsf[lr][lk + 0] = bv.x; Bsf[lr][lk + 1] = bv.y;
        Bsf[lr][lk + 2] = bv.z; Bsf[lr][lk + 3] = bv.w;
        __syncthreads();
#pragma unroll
        for (int k = 0; k < BK; ++k) {
            float a[4], bb[4];
#pragma unroll
            for (int i = 0; i < 4; ++i) a[i] = Asf[ty + 16 * i][k];
#pragma unroll
            for (int j = 0; j < 4; ++j) bb[j] = Bsf[tx + 16 * j][k];
#pragma unroll
            for (int i = 0; i < 4; ++i)
#pragma unroll
                for (int j = 0; j < 4; ++j)
                    acc[i][j] += a[i] * bb[j];
        }
        __syncthreads();
    }
#pragma unroll
    for (int i = 0; i < 4; ++i)
#pragma unroll
        for (int j = 0; j < 4; ++j)
            C[(long)(m0 + ty + 16 * i) * ldc + n0 + tx + 16 * j] = acc[i][j];
}

// ---------------------------------------------------------------
// h = 2*silu(bn(g2 + pw_b)) + pe(l, f)   (in-place on g2)
// ---------------------------------------------------------------
__global__ __launch_bounds__(256) void ep_h(
    float* __restrict__ g2, const float* __restrict__ pw_b,
    const float* __restrict__ bn_g, const float* __restrict__ bn_b,
    const float* __restrict__ bn_m, const float* __restrict__ bn_v)
{
    int idx = blockIdx.x * 256 + threadIdx.x;
    int f = idx & 511;
    int l = (idx >> 9) & 511;
    float v = g2[idx] + pw_b[l];
    float sc = bn_g[l] * rsqrtf(bn_v[l] + 1e-5f);
    v = (v - bn_m[l]) * sc + bn_b[l];
    v = v / (1.f + __expf(-v));
    int i2 = f & ~1;
    float dv = __expf((float)i2 * (-9.210340371976184f / 512.f));
    float ang = (float)l * dv;
    float pe = (f & 1) ? cosf(ang) : sinf(ang);
    g2[idx] = 2.f * v + pe;
}

// ---------------------------------------------------------------
// Causal depthwise conv k=4 over sequence + SiLU.
// ---------------------------------------------------------------
__global__ __launch_bounds__(256) void ep_conv_silu(
    const float* __restrict__ xzbuf, const float* __restrict__ cw,
    const float* __restrict__ cb, float* __restrict__ xcb)
{
    int idx = blockIdx.x * 256 + threadIdx.x;
    int d = idx & (DI - 1);
    int l = (idx >> 10) & (L_SEQ - 1);
    int b = idx >> 19;
    const float* xin = xzbuf + ((long)b * L_SEQ) * (2 * DI) + d;
    float acc = cb[d];
#pragma unroll
    for (int k = 0; k < 4; ++k) {
        int ls = l - 3 + k;
        if (ls >= 0) acc += cw[d * 4 + k] * xin[(long)ls * (2 * DI)];
    }
    xcb[idx] = acc / (1.f + __expf(-acc));
}

// ---------------------------------------------------------------
// softplus(dt + bias) in-place
// ---------------------------------------------------------------
__global__ __launch_bounds__(256) void ep_softplus(
    float* __restrict__ dtb, const float* __restrict__ dt_b)
{
    int idx = blockIdx.x * 256 + threadIdx.x;
    int d = idx & (DI - 1);
    float v = dtb[idx] + dt_b[d];
    dtb[idx] = fmaxf(v, 0.f) + log1pf(expf(-fabsf(v)));
}

// ---------------------------------------------------------------
// SSM scan v3: state-parallel, prefetch depth 2, exp hoisted
// off the carried chain. One thread per (b, d, n).
// ---------------------------------------------------------------
__global__ __launch_bounds__(256) void k_scan(
    const float* __restrict__ dtb, const float* __restrict__ xcb,
    const float* __restrict__ xdbl, const float* __restrict__ xzbuf,
    const float* __restrict__ A_log, const float* __restrict__ Dv,
    float* __restrict__ ybuf)
{
    int b = blockIdx.y;
    int tid = threadIdx.x;
    int n = tid & 15;
    int d = blockIdx.x * 16 + (tid >> 4);

    float An = -__expf(A_log[d * NS + n]);
    float Dd = Dv[d];
    float h = 0.f;

    long rbase = (long)b * L_SEQ;
    const float* dtp = dtb + rbase * DI + d;
    const float* xcp = xcb + rbase * DI + d;
    const float* zp  = xzbuf + rbase * (2 * DI) + DI + d;
    const float* bp  = xdbl + rbase * 64 + RK + n;

    float dt0 = dtp[0], xc0 = xcp[0], B0 = bp[0], C0 = bp[16], z0 = zp[0];
    float dt1 = dtp[DI], xc1 = xcp[DI], B1 = bp[64], C1 = bp[80], z1 = zp[2 * DI];
    float dA0 = __expf(dt0 * An);

    for (int l = 0; l < L_SEQ; ++l) {
        int l2 = (l + 2 < L_SEQ) ? (l + 2) : (L_SEQ - 1);
        float dt2 = dtp[(long)l2 * DI];
        float xc2 = xcp[(long)l2 * DI];
        float B2  = bp[(long)l2 * 64];
        float C2  = bp[(long)l2 * 64 + 16];
        float z2  = zp[(long)l2 * 2 * DI];

        float dA1 = __expf(dt1 * An);        // next step's dA, independent
        h = fmaf(dA0, h, dt0 * B0 * xc0);
        float p = h * C0;
        p += __shfl_xor(p, 1);
        p += __shfl_xor(p, 2);
        p += __shfl_xor(p, 4);
        p += __shfl_xor(p, 8);
        if (n == 0) {
            float gt = z0 / (1.f + __expf(-z0));
            ybuf[(rbase + l) * DI + d] = (p + xc0 * Dd) * gt;
        }
        dt0 = dt1; xc0 = xc1; B0 = B1; C0 = C1; z0 = z1; dA0 = dA1;
        dt1 = dt2; xc1 = xc2; B1 = B2; C1 = C2; z1 = z2;
    }
}

// ---------------------------------------------------------------
extern "C" void kernel_launch(void* const* d_in, const int* in_sizes, int n_in,
                              void* d_out, int out_size, void* d_ws, size_t ws_size,
                              hipStream_t stream)
{
    const float* x        = (const float*)d_in[0];
    const float* dw_w     = (const float*)d_in[1];
    const float* dw_b     = (const float*)d_in[2];
    const float* pw_w     = (const float*)d_in[3];
    const float* pw_b     = (const float*)d_in[4];
    const float* bn_g     = (const float*)d_in[5];
    const float* bn_b     = (const float*)d_in[6];
    const float* bn_m     = (const float*)d_in[7];
    const float* bn_v     = (const float*)d_in[8];
    const float* in_proj_w  = (const float*)d_in[9];
    const float* conv1d_w   = (const float*)d_in[10];
    const float* conv1d_b   = (const float*)d_in[11];
    const float* x_proj_w   = (const float*)d_in[12];
    const float* dt_proj_w  = (const float*)d_in[13];
    const float* dt_proj_b  = (const float*)d_in[14];
    const float* A_log      = (const float*)d_in[15];
    const float* Dvec       = (const float*)d_in[16];
    const float* out_proj_w = (const float*)d_in[17];
    float* out = (float*)d_out;

    char* ws = (char*)d_ws;
    float* h1t  = (float*)(ws + 0);              //  8 MB  [B][FD][C]
    float* g2   = (float*)(ws + 8388608);        //  8 MB  [B][L][FD]
    float* dtb  = (float*)(ws + 0);              // 16 MB  [B][L][DI]  (reuse)
    float* xzb  = (float*)(ws + 16777216);       // 32 MB  [B][L][2*DI]
    float* xcb  = (float*)(ws + 50331648);       // 16 MB  [B][L][DI]
    float* xdbl = (float*)(ws + 67108864);       //  1 MB  [B][L][64]
    float* ybuf = (float*)(ws + 68157440);       // 16 MB  [B][L][DI]

    // 1. depthwise + transpose
    {
        dim3 g(FD / 32, IN_CH / 32, BATCH), blk(32, 8);
        hipLaunchKernelGGL(k_dw_transpose, g, blk, 0, stream, x, dw_w, dw_b, h1t);
    }
    // 2. pointwise GEMM (bf16 MFMA, batched): M=512,N=512,K=512
    {
        dim3 g(512 / 128, 512 / 128, BATCH);
        hipLaunchKernelGGL(gemm_bf16, g, dim3(256), 0, stream,
                           pw_w, h1t, g2, IN_CH, IN_CH, IN_CH, FD,
                           0L, (long)FD * IN_CH, (long)IN_CH * FD);
    }
    // 3. epilogue
    hipLaunchKernelGGL(ep_h, dim3(BATCH * L_SEQ * FD / 256), dim3(256), 0, stream,
                       g2, pw_b, bn_g, bn_b, bn_m, bn_v);
    // 4. in_proj GEMM (bf16 MFMA): M=4096,N=2048,K=512
    {
        dim3 g(2048 / 128, (BATCH * L_SEQ) / 128, 1);
        hipLaunchKernelGGL(gemm_bf16, g, dim3(256), 0, stream,
                           g2, in_proj_w, xzb, FD, FD, FD, 2048, 0L, 0L, 0L);
    }
    // 5. causal conv + silu -> xc
    hipLaunchKernelGGL(ep_conv_silu, dim3(BATCH * L_SEQ * DI / 256), dim3(256), 0, stream,
                       xzb, conv1d_w, conv1d_b, xcb);
    // 6. x_proj GEMM (fp32, N=64): M=4096,N=64,K=1024
    {
        dim3 g(64 / BN, (BATCH * L_SEQ) / BM, 1);
        hipLaunchKernelGGL(gemm_nt, g, dim3(256), 0, stream,
                           xcb, x_proj_w, xdbl, BATCH * L_SEQ, 64, DI, DI, DI, 64,
                           0L, 0L, 0L);
    }
    // 7. dt_proj GEMM (fp32 — exp-sensitive path): M=4096,N=1024,K=32
    {
        dim3 g(DI / BN, (BATCH * L_SEQ) / BM, 1);
        hipLaunchKernelGGL(gemm_nt, g, dim3(256), 0, stream,
                           xdbl, dt_proj_w, dtb, BATCH * L_SEQ, DI, RK, 64, RK, DI,
                           0L, 0L, 0L);
    }
    // 8. softplus
    hipLaunchKernelGGL(ep_softplus, dim3(BATCH * L_SEQ * DI / 256), dim3(256), 0, stream,
                       dtb, dt_proj_b);
    // 9. scan v3
    {
        dim3 g(DI / 16, BATCH);
        hipLaunchKernelGGL(k_scan, g, dim3(256), 0, stream,
                           dtb, xcb, xdbl, xzb, A_log, Dvec, ybuf);
    }
    // 10. out_proj GEMM (bf16 MFMA): M=4096,N=512,K=1024
    {
        dim3 g(512 / 128, (BATCH * L_SEQ) / 128, 1);
        hipLaunchKernelGGL(gemm_bf16, g, dim3(256), 0, stream,
                           ybuf, out_proj_w, out, DI, DI, DI, FD, 0L, 0L, 0L);
    }
}

// Round 4
// 264.503 us; speedup vs baseline: 2.7969x; 1.4870x over previous
//
#include <hip/hip_runtime.h>
#include <hip/hip_bf16.h>
#include <math.h>

#define BATCH 8
#define IN_CH 512
#define L0 1024
#define FD 512
#define L_SEQ 512
#define DI 1024
#define NS 16
#define RK 32

// scan chunking
#define LC 32      // chunk length
#define NCH 16     // chunks per (b,d)
#define DG 16      // d-channels per block

typedef __attribute__((ext_vector_type(4))) float f32x4;
typedef __attribute__((ext_vector_type(8))) short s16x8;

__device__ __forceinline__ unsigned short f2bf(float f) {
    union { float f; unsigned int u; } v; v.f = f;
    unsigned int u = v.u;
    return (unsigned short)((u + 0x7FFFu + ((u >> 16) & 1u)) >> 16);  // RNE
}
__device__ __forceinline__ unsigned int pk2(float x, float y) {
    return (unsigned int)f2bf(x) | ((unsigned int)f2bf(y) << 16);
}
__device__ __forceinline__ float bf2f(unsigned short u) {
    union { unsigned int w; float f; } v; v.w = (unsigned int)u << 16;
    return v.f;
}

// ---------------------------------------------------------------
// Kernel 1: depthwise conv (k=2, s=2) + transpose  -> h1t[b, f, c]
// ---------------------------------------------------------------
__global__ __launch_bounds__(256) void k_dw_transpose(
    const float* __restrict__ x, const float* __restrict__ dww,
    const float* __restrict__ dwb, float* __restrict__ h1t)
{
    int b = blockIdx.z;
    int c0 = blockIdx.y * 32;
    int f0 = blockIdx.x * 32;
    __shared__ float t[32][33];
    int tx = threadIdx.x, ty = threadIdx.y;
#pragma unroll
    for (int i = 0; i < 4; ++i) {
        int cc = ty + 8 * i;
        int c = c0 + cc, f = f0 + tx;
        const float* xp = x + ((long)b * IN_CH + c) * L0 + 2 * f;
        t[cc][tx] = xp[0] * dww[c * 2 + 0] + xp[1] * dww[c * 2 + 1] + dwb[c];
    }
    __syncthreads();
#pragma unroll
    for (int i = 0; i < 4; ++i) {
        int ff = ty + 8 * i;
        h1t[((long)b * FD + f0 + ff) * IN_CH + c0 + tx] = t[tx][ff];
    }
}

// ---------------------------------------------------------------
// bf16 MFMA GEMM (NT): C[m,n] = sum_k A[m,k]*B[n,k], fp32 in/out.
// 128x128 tile, BK=32, 256 threads = 4 waves (2x2 of 64x64).
// ---------------------------------------------------------------
__global__ __launch_bounds__(256) void gemm_bf16(
    const float* __restrict__ A, const float* __restrict__ B,
    float* __restrict__ C,
    int K, int lda, int ldb, int ldc, long sA, long sB, long sC)
{
    int bz = blockIdx.z;
    A += (long)bz * sA; B += (long)bz * sB; C += (long)bz * sC;
    int m0 = blockIdx.y * 128, n0 = blockIdx.x * 128;

    __shared__ __align__(16) unsigned short As[128][40];
    __shared__ __align__(16) unsigned short Bs[128][40];

    int tid = threadIdx.x;
    int row = tid >> 1, half = tid & 1;
    int lane = tid & 63, wid = tid >> 6;
    int wm = wid >> 1, wn = wid & 1;
    int lm = lane & 15, g = lane >> 4;

    f32x4 zero = {0.f, 0.f, 0.f, 0.f};
    f32x4 acc[4][4];
#pragma unroll
    for (int i = 0; i < 4; ++i)
#pragma unroll
        for (int j = 0; j < 4; ++j) acc[i][j] = zero;

    const float* ga = A + (long)(m0 + row) * lda + half * 16;
    const float* gb = B + (long)(n0 + row) * ldb + half * 16;

    for (int k0 = 0; k0 < K; k0 += 32) {
        float4 a0 = *(const float4*)(ga + k0);
        float4 a1 = *(const float4*)(ga + k0 + 4);
        float4 a2 = *(const float4*)(ga + k0 + 8);
        float4 a3 = *(const float4*)(ga + k0 + 12);
        float4 b0 = *(const float4*)(gb + k0);
        float4 b1 = *(const float4*)(gb + k0 + 4);
        float4 b2 = *(const float4*)(gb + k0 + 8);
        float4 b3 = *(const float4*)(gb + k0 + 12);
        uint4 pa0, pa1, pb0, pb1;
        pa0.x = pk2(a0.x, a0.y); pa0.y = pk2(a0.z, a0.w);
        pa0.z = pk2(a1.x, a1.y); pa0.w = pk2(a1.z, a1.w);
        pa1.x = pk2(a2.x, a2.y); pa1.y = pk2(a2.z, a2.w);
        pa1.z = pk2(a3.x, a3.y); pa1.w = pk2(a3.z, a3.w);
        pb0.x = pk2(b0.x, b0.y); pb0.y = pk2(b0.z, b0.w);
        pb0.z = pk2(b1.x, b1.y); pb0.w = pk2(b1.z, b1.w);
        pb1.x = pk2(b2.x, b2.y); pb1.y = pk2(b2.z, b2.w);
        pb1.z = pk2(b3.x, b3.y); pb1.w = pk2(b3.z, b3.w);
        *(uint4*)&As[row][half * 16]     = pa0;
        *(uint4*)&As[row][half * 16 + 8] = pa1;
        *(uint4*)&Bs[row][half * 16]     = pb0;
        *(uint4*)&Bs[row][half * 16 + 8] = pb1;
        __syncthreads();

        s16x8 av[4], bv[4];
#pragma unroll
        for (int im = 0; im < 4; ++im)
            av[im] = *(const s16x8*)&As[wm * 64 + im * 16 + lm][g * 8];
#pragma unroll
        for (int jn = 0; jn < 4; ++jn)
            bv[jn] = *(const s16x8*)&Bs[wn * 64 + jn * 16 + lm][g * 8];
#pragma unroll
        for (int im = 0; im < 4; ++im)
#pragma unroll
            for (int jn = 0; jn < 4; ++jn)
                acc[im][jn] = __builtin_amdgcn_mfma_f32_16x16x32_bf16(
                    av[im], bv[jn], acc[im][jn], 0, 0, 0);
        __syncthreads();
    }
#pragma unroll
    for (int im = 0; im < 4; ++im)
#pragma unroll
        for (int jn = 0; jn < 4; ++jn)
#pragma unroll
            for (int r = 0; r < 4; ++r)
                C[(long)(m0 + wm * 64 + im * 16 + g * 4 + r) * ldc
                  + n0 + wn * 64 + jn * 16 + lm] = acc[im][jn][r];
}

// ---------------------------------------------------------------
// x_proj GEMM via bf16 hi/lo split (fp32-class accuracy on MFMA).
// C[m,n] = sum_k A[m,k]*B[n,k]; N = 64 fixed; tile 128(M)x64(N), BK=32.
// 4 waves = 2x2, wave-tile 64x32.
// ---------------------------------------------------------------
__global__ __launch_bounds__(256) void gemm_xproj(
    const float* __restrict__ A, const float* __restrict__ B,
    float* __restrict__ C, int K, int lda, int ldb, int ldc)
{
    int m0 = blockIdx.x * 128;
    __shared__ __align__(16) unsigned short Ah[128][40], Al[128][40];
    __shared__ __align__(16) unsigned short Bh[64][40],  Bl[64][40];

    int tid = threadIdx.x;
    int row = tid >> 1, half = tid & 1;
    int lane = tid & 63, wid = tid >> 6;
    int wm = wid >> 1, wn = wid & 1;
    int lm = lane & 15, g = lane >> 4;

    f32x4 zero = {0.f, 0.f, 0.f, 0.f};
    f32x4 acc[4][2];
#pragma unroll
    for (int i = 0; i < 4; ++i) { acc[i][0] = zero; acc[i][1] = zero; }

    const float* ga = A + (long)(m0 + row) * lda + half * 16;
    const float* gb = B + (long)(row & 63) * ldb + half * 16;  // valid rows for tid<128

    for (int k0 = 0; k0 < K; k0 += 32) {
        float buf[16];
        *(float4*)&buf[0]  = *(const float4*)(ga + k0);
        *(float4*)&buf[4]  = *(const float4*)(ga + k0 + 4);
        *(float4*)&buf[8]  = *(const float4*)(ga + k0 + 8);
        *(float4*)&buf[12] = *(const float4*)(ga + k0 + 12);
        unsigned int* dh = (unsigned int*)&Ah[row][half * 16];
        unsigned int* dl = (unsigned int*)&Al[row][half * 16];
#pragma unroll
        for (int q = 0; q < 8; ++q) {
            unsigned short h0 = f2bf(buf[2 * q]), h1 = f2bf(buf[2 * q + 1]);
            dh[q] = (unsigned int)h0 | ((unsigned int)h1 << 16);
            float l0 = buf[2 * q] - bf2f(h0), l1 = buf[2 * q + 1] - bf2f(h1);
            dl[q] = (unsigned int)f2bf(l0) | ((unsigned int)f2bf(l1) << 16);
        }
        if (tid < 128) {
            float bufb[16];
            *(float4*)&bufb[0]  = *(const float4*)(gb + k0);
            *(float4*)&bufb[4]  = *(const float4*)(gb + k0 + 4);
            *(float4*)&bufb[8]  = *(const float4*)(gb + k0 + 8);
            *(float4*)&bufb[12] = *(const float4*)(gb + k0 + 12);
            unsigned int* bh = (unsigned int*)&Bh[row][half * 16];
            unsigned int* bl = (unsigned int*)&Bl[row][half * 16];
#pragma unroll
            for (int q = 0; q < 8; ++q) {
                unsigned short h0 = f2bf(bufb[2 * q]), h1 = f2bf(bufb[2 * q + 1]);
                bh[q] = (unsigned int)h0 | ((unsigned int)h1 << 16);
                float l0 = bufb[2 * q] - bf2f(h0), l1 = bufb[2 * q + 1] - bf2f(h1);
                bl[q] = (unsigned int)f2bf(l0) | ((unsigned int)f2bf(l1) << 16);
            }
        }
        __syncthreads();

        s16x8 avh[4], avl[4], bvh[2], bvl[2];
#pragma unroll
        for (int im = 0; im < 4; ++im) {
            avh[im] = *(const s16x8*)&Ah[wm * 64 + im * 16 + lm][g * 8];
            avl[im] = *(const s16x8*)&Al[wm * 64 + im * 16 + lm][g * 8];
        }
#pragma unroll
        for (int jn = 0; jn < 2; ++jn) {
            bvh[jn] = *(const s16x8*)&Bh[wn * 32 + jn * 16 + lm][g * 8];
            bvl[jn] = *(const s16x8*)&Bl[wn * 32 + jn * 16 + lm][g * 8];
        }
#pragma unroll
        for (int im = 0; im < 4; ++im)
#pragma unroll
            for (int jn = 0; jn < 2; ++jn) {
                acc[im][jn] = __builtin_amdgcn_mfma_f32_16x16x32_bf16(
                    avl[im], bvh[jn], acc[im][jn], 0, 0, 0);
                acc[im][jn] = __builtin_amdgcn_mfma_f32_16x16x32_bf16(
                    avh[im], bvl[jn], acc[im][jn], 0, 0, 0);
                acc[im][jn] = __builtin_amdgcn_mfma_f32_16x16x32_bf16(
                    avh[im], bvh[jn], acc[im][jn], 0, 0, 0);
            }
        __syncthreads();
    }
#pragma unroll
    for (int im = 0; im < 4; ++im)
#pragma unroll
        for (int jn = 0; jn < 2; ++jn)
#pragma unroll
            for (int r = 0; r < 4; ++r)
                C[(long)(m0 + wm * 64 + im * 16 + g * 4 + r) * ldc
                  + wn * 32 + jn * 16 + lm] = acc[im][jn][r];
}

// ---------------------------------------------------------------
// Generic fp32 GEMM (NT) — used for dt_proj (K=32) only.
// ---------------------------------------------------------------
#define BM 64
#define BN 64
#define BK 16

__global__ __launch_bounds__(256) void gemm_nt(
    const float* __restrict__ A, const float* __restrict__ B,
    float* __restrict__ C,
    int M, int N, int K, int lda, int ldb, int ldc,
    long sA, long sB, long sC)
{
    int bz = blockIdx.z;
    A += (long)bz * sA; B += (long)bz * sB; C += (long)bz * sC;
    int m0 = blockIdx.y * BM;
    int n0 = blockIdx.x * BN;

    __shared__ float Asf[BM][BK + 1];
    __shared__ float Bsf[BN][BK + 1];

    int tid = threadIdx.x;
    int lr = tid >> 2;
    int lk = (tid & 3) * 4;
    int tx = tid & 15;
    int ty = tid >> 4;

    float acc[4][4] = {};

    for (int k0 = 0; k0 < K; k0 += BK) {
        float4 av = *(const float4*)(A + (long)(m0 + lr) * lda + k0 + lk);
        Asf[lr][lk + 0] = av.x; Asf[lr][lk + 1] = av.y;
        Asf[lr][lk + 2] = av.z; Asf[lr][lk + 3] = av.w;
        float4 bv = *(const float4*)(B + (long)(n0 + lr) * ldb + k0 + lk);
        Bsf[lr][lk + 0] = bv.x; Bsf[lr][lk + 1] = bv.y;
        Bsf[lr][lk + 2] = bv.z; Bsf[lr][lk + 3] = bv.w;
        __syncthreads();
#pragma unroll
        for (int k = 0; k < BK; ++k) {
            float a[4], bb[4];
#pragma unroll
            for (int i = 0; i < 4; ++i) a[i] = Asf[ty + 16 * i][k];
#pragma unroll
            for (int j = 0; j < 4; ++j) bb[j] = Bsf[tx + 16 * j][k];
#pragma unroll
            for (int i = 0; i < 4; ++i)
#pragma unroll
                for (int j = 0; j < 4; ++j)
                    acc[i][j] += a[i] * bb[j];
        }
        __syncthreads();
    }
#pragma unroll
    for (int i = 0; i < 4; ++i)
#pragma unroll
        for (int j = 0; j < 4; ++j)
            C[(long)(m0 + ty + 16 * i) * ldc + n0 + tx + 16 * j] = acc[i][j];
}

// ---------------------------------------------------------------
// h = 2*silu(bn(g2 + pw_b)) + pe(l, f)   (in-place on g2)
// ---------------------------------------------------------------
__global__ __launch_bounds__(256) void ep_h(
    float* __restrict__ g2, const float* __restrict__ pw_b,
    const float* __restrict__ bn_g, const float* __restrict__ bn_b,
    const float* __restrict__ bn_m, const float* __restrict__ bn_v)
{
    int idx = blockIdx.x * 256 + threadIdx.x;
    int f = idx & 511;
    int l = (idx >> 9) & 511;
    float v = g2[idx] + pw_b[l];
    float sc = bn_g[l] * rsqrtf(bn_v[l] + 1e-5f);
    v = (v - bn_m[l]) * sc + bn_b[l];
    v = v / (1.f + __expf(-v));
    int i2 = f & ~1;
    float dv = __expf((float)i2 * (-9.210340371976184f / 512.f));
    float ang = (float)l * dv;
    float pe = (f & 1) ? cosf(ang) : sinf(ang);
    g2[idx] = 2.f * v + pe;
}

// ---------------------------------------------------------------
// Causal depthwise conv k=4 over sequence + SiLU.
// ---------------------------------------------------------------
__global__ __launch_bounds__(256) void ep_conv_silu(
    const float* __restrict__ xzbuf, const float* __restrict__ cw,
    const float* __restrict__ cb, float* __restrict__ xcb)
{
    int idx = blockIdx.x * 256 + threadIdx.x;
    int d = idx & (DI - 1);
    int l = (idx >> 10) & (L_SEQ - 1);
    int b = idx >> 19;
    const float* xin = xzbuf + ((long)b * L_SEQ) * (2 * DI) + d;
    float acc = cb[d];
#pragma unroll
    for (int k = 0; k < 4; ++k) {
        int ls = l - 3 + k;
        if (ls >= 0) acc += cw[d * 4 + k] * xin[(long)ls * (2 * DI)];
    }
    xcb[idx] = acc / (1.f + __expf(-acc));
}

// ---------------------------------------------------------------
// SSM scan v4: chunked associative scan, all 16 states in registers.
// Block = 256 threads = DG(16) d-channels x NCH(16) chunks of LC(32).
// Fused: dt bias + softplus, D-residual, z-gate.
// Pass1: per-chunk aggregates (Aagg = exp(An*sum dt), Bagg).
// LDS boundary scan over chunks, then Pass2 re-applies and emits y.
// ---------------------------------------------------------------
__global__ __launch_bounds__(256) void k_scan(
    const float* __restrict__ dtraw, const float* __restrict__ dt_b,
    const float* __restrict__ xcb, const float* __restrict__ xdbl,
    const float* __restrict__ xzbuf,
    const float* __restrict__ A_log, const float* __restrict__ Dv,
    float* __restrict__ ybuf)
{
    int b = blockIdx.y;
    int tid = threadIdx.x;
    int c = tid >> 4;        // chunk
    int dg = tid & 15;       // d within block
    int d = blockIdx.x * DG + dg;

    __shared__ float sA[DG][16][NCH + 1];
    __shared__ float sB[DG][16][NCH + 1];

    float An[16];
    {
        const float4* ap = (const float4*)(A_log + d * 16);
#pragma unroll
        for (int q = 0; q < 4; ++q) {
            float4 v = ap[q];
            An[q * 4 + 0] = -__expf(v.x); An[q * 4 + 1] = -__expf(v.y);
            An[q * 4 + 2] = -__expf(v.z); An[q * 4 + 3] = -__expf(v.w);
        }
    }
    float bias = dt_b[d];

    long rbase = (long)b * L_SEQ + c * LC;
    const float* dtp = dtraw + rbase * DI + d;
    const float* xcp = xcb + rbase * DI + d;
    const float* bcp = xdbl + rbase * 64 + RK;   // B: +0..15, C: +16..31

    // ---- pass 1: chunk aggregates ----
    float S = 0.f;
    float Bagg[16];
#pragma unroll
    for (int n = 0; n < 16; ++n) Bagg[n] = 0.f;
#pragma unroll 2
    for (int l = 0; l < LC; ++l) {
        float v = dtp[(long)l * DI] + bias;
        float dtv = fmaxf(v, 0.f) + log1pf(__expf(-fabsf(v)));
        float xcv = xcp[(long)l * DI];
        const float4* br = (const float4*)(bcp + (long)l * 64);
        float4 b0 = br[0], b1 = br[1], b2 = br[2], b3 = br[3];
        float Bv[16] = {b0.x, b0.y, b0.z, b0.w, b1.x, b1.y, b1.z, b1.w,
                        b2.x, b2.y, b2.z, b2.w, b3.x, b3.y, b3.z, b3.w};
        float u = dtv * xcv;
        S += dtv;
#pragma unroll
        for (int n = 0; n < 16; ++n) {
            float dA = __expf(dtv * An[n]);
            Bagg[n] = fmaf(dA, Bagg[n], u * Bv[n]);
        }
    }
#pragma unroll
    for (int n = 0; n < 16; ++n) {
        sA[dg][n][c] = __expf(S * An[n]);
        sB[dg][n][c] = Bagg[n];
    }
    __syncthreads();

    // ---- boundary scan: thread owns (dg2, n2), serial over chunks ----
    {
        int dg2 = tid >> 4, n2 = tid & 15;
        float hh = 0.f;
#pragma unroll
        for (int cc = 0; cc < NCH; ++cc) {
            float a = sA[dg2][n2][cc], bb2 = sB[dg2][n2][cc];
            sA[dg2][n2][cc] = hh;          // exclusive prefix = h_in
            hh = fmaf(a, hh, bb2);
        }
    }
    __syncthreads();

    float h[16];
#pragma unroll
    for (int n = 0; n < 16; ++n) h[n] = sA[dg][n][c];

    // ---- pass 2: re-apply with correct h_in, emit y ----
    const float* zp = xzbuf + rbase * (2 * DI) + DI + d;
    float Dd = Dv[d];
    float* yp = ybuf + rbase * DI + d;
#pragma unroll 2
    for (int l = 0; l < LC; ++l) {
        float v = dtp[(long)l * DI] + bias;
        float dtv = fmaxf(v, 0.f) + log1pf(__expf(-fabsf(v)));
        float xcv = xcp[(long)l * DI];
        float zv = zp[(long)l * 2 * DI];
        const float4* br = (const float4*)(bcp + (long)l * 64);
        float4 b0 = br[0], b1 = br[1], b2 = br[2], b3 = br[3];
        float4 c0 = br[4], c1 = br[5], c2 = br[6], c3 = br[7];
        float Bv[16] = {b0.x, b0.y, b0.z, b0.w, b1.x, b1.y, b1.z, b1.w,
                        b2.x, b2.y, b2.z, b2.w, b3.x, b3.y, b3.z, b3.w};
        float Cv[16] = {c0.x, c0.y, c0.z, c0.w, c1.x, c1.y, c1.z, c1.w,
                        c2.x, c2.y, c2.z, c2.w, c3.x, c3.y, c3.z, c3.w};
        float u = dtv * xcv;
        float y = 0.f;
#pragma unroll
        for (int n = 0; n < 16; ++n) {
            float dA = __expf(dtv * An[n]);
            h[n] = fmaf(dA, h[n], u * Bv[n]);
            y = fmaf(h[n], Cv[n], y);
        }
        float gt = zv / (1.f + __expf(-zv));
        yp[(long)l * DI] = (y + xcv * Dd) * gt;
    }
}

// ---------------------------------------------------------------
extern "C" void kernel_launch(void* const* d_in, const int* in_sizes, int n_in,
                              void* d_out, int out_size, void* d_ws, size_t ws_size,
                              hipStream_t stream)
{
    const float* x        = (const float*)d_in[0];
    const float* dw_w     = (const float*)d_in[1];
    const float* dw_b     = (const float*)d_in[2];
    const float* pw_w     = (const float*)d_in[3];
    const float* pw_b     = (const float*)d_in[4];
    const float* bn_g     = (const float*)d_in[5];
    const float* bn_b     = (const float*)d_in[6];
    const float* bn_m     = (const float*)d_in[7];
    const float* bn_v     = (const float*)d_in[8];
    const float* in_proj_w  = (const float*)d_in[9];
    const float* conv1d_w   = (const float*)d_in[10];
    const float* conv1d_b   = (const float*)d_in[11];
    const float* x_proj_w   = (const float*)d_in[12];
    const float* dt_proj_w  = (const float*)d_in[13];
    const float* dt_proj_b  = (const float*)d_in[14];
    const float* A_log      = (const float*)d_in[15];
    const float* Dvec       = (const float*)d_in[16];
    const float* out_proj_w = (const float*)d_in[17];
    float* out = (float*)d_out;

    char* ws = (char*)d_ws;
    float* h1t  = (float*)(ws + 0);              //  8 MB  [B][FD][C]
    float* g2   = (float*)(ws + 8388608);        //  8 MB  [B][L][FD]
    float* dtb  = (float*)(ws + 0);              // 16 MB  [B][L][DI]  (reuse, raw dt)
    float* xzb  = (float*)(ws + 16777216);       // 32 MB  [B][L][2*DI]
    float* xcb  = (float*)(ws + 50331648);       // 16 MB  [B][L][DI]
    float* xdbl = (float*)(ws + 67108864);       //  1 MB  [B][L][64]
    float* ybuf = (float*)(ws + 68157440);       // 16 MB  [B][L][DI]

    // 1. depthwise + transpose
    {
        dim3 g(FD / 32, IN_CH / 32, BATCH), blk(32, 8);
        hipLaunchKernelGGL(k_dw_transpose, g, blk, 0, stream, x, dw_w, dw_b, h1t);
    }
    // 2. pointwise GEMM (bf16 MFMA, batched)
    {
        dim3 g(512 / 128, 512 / 128, BATCH);
        hipLaunchKernelGGL(gemm_bf16, g, dim3(256), 0, stream,
                           pw_w, h1t, g2, IN_CH, IN_CH, IN_CH, FD,
                           0L, (long)FD * IN_CH, (long)IN_CH * FD);
    }
    // 3. epilogue
    hipLaunchKernelGGL(ep_h, dim3(BATCH * L_SEQ * FD / 256), dim3(256), 0, stream,
                       g2, pw_b, bn_g, bn_b, bn_m, bn_v);
    // 4. in_proj GEMM (bf16 MFMA)
    {
        dim3 g(2048 / 128, (BATCH * L_SEQ) / 128, 1);
        hipLaunchKernelGGL(gemm_bf16, g, dim3(256), 0, stream,
                           g2, in_proj_w, xzb, FD, FD, FD, 2048, 0L, 0L, 0L);
    }
    // 5. causal conv + silu -> xc
    hipLaunchKernelGGL(ep_conv_silu, dim3(BATCH * L_SEQ * DI / 256), dim3(256), 0, stream,
                       xzb, conv1d_w, conv1d_b, xcb);
    // 6. x_proj GEMM (bf16 hi/lo MFMA): M=4096, N=64, K=1024
    hipLaunchKernelGGL(gemm_xproj, dim3((BATCH * L_SEQ) / 128), dim3(256), 0, stream,
                       xcb, x_proj_w, xdbl, DI, DI, DI, 64);
    // 7. dt_proj GEMM (fp32, raw — bias+softplus fused into scan)
    {
        dim3 g(DI / BN, (BATCH * L_SEQ) / BM, 1);
        hipLaunchKernelGGL(gemm_nt, g, dim3(256), 0, stream,
                           xdbl, dt_proj_w, dtb, BATCH * L_SEQ, DI, RK, 64, RK, DI,
                           0L, 0L, 0L);
    }
    // 8. scan v4 (chunked)
    {
        dim3 g(DI / DG, BATCH);
        hipLaunchKernelGGL(k_scan, g, dim3(256), 0, stream,
                           dtb, dt_proj_b, xcb, xdbl, xzb, A_log, Dvec, ybuf);
    }
    // 9. out_proj GEMM (bf16 MFMA)
    {
        dim3 g(512 / 128, (BATCH * L_SEQ) / 128, 1);
        hipLaunchKernelGGL(gemm_bf16, g, dim3(256), 0, stream,
                           ybuf, out_proj_w, out, DI, DI, DI, FD, 0L, 0L, 0L);
    }
}